// Round 3
// baseline (739.256 us; speedup 1.0000x reference)
//
#include <hip/hip_runtime.h>

#define N_IC 10
#define N_OC 32
#define PPB 128          // points per block in k1
#define BLK 256
#define PAD 11           // LDS stride pad: 11 coprime 32 -> conflict-free
#define NPIL 50000

typedef float f4 __attribute__((ext_vector_type(4)));

// k1: fused linear + BN(inference) + relu. 4 channels per thread, f4 stores,
// f4 filter-read + filtered scalar atomicMax into pillar buffer.
__global__ __launch_bounds__(BLK) void pfn_k1(
    const float* __restrict__ in, const int* __restrict__ unq,
    const float* __restrict__ W, const float* __restrict__ gamma,
    const float* __restrict__ beta, const float* __restrict__ rmean,
    const float* __restrict__ rvar,
    float* __restrict__ out, unsigned* __restrict__ pmax, int n)
{
    __shared__ float sW[N_OC][N_IC];
    __shared__ float sB[N_OC];
    __shared__ float sIn[PPB][PAD];
    __shared__ int   sPil[PPB];

    const int t = threadIdx.x;
    // fold BN into weights (32 threads, once per block; precise inv-std)
    if (t < N_OC) {
        float s = gamma[t] / sqrtf(rvar[t] + 1e-3f);
        sB[t] = fmaf(-rmean[t], s, beta[t]);
        #pragma unroll
        for (int k = 0; k < N_IC; ++k) sW[t][k] = W[t * N_IC + k] * s;
    }
    const long long base = (long long)blockIdx.x * PPB;
    // stage 128 points x 10 ch, coalesced global read -> padded LDS (NT: read-once stream)
    for (int i = t; i < PPB * N_IC; i += BLK) {
        int p = i / N_IC;
        int k = i - p * N_IC;
        long long gp = base + p;
        sIn[p][k] = (gp < (long long)n) ? __builtin_nontemporal_load(&in[gp * N_IC + k]) : 0.f;
    }
    if (t < PPB) {
        long long gp = base + t;
        sPil[t] = (gp < (long long)n) ? unq[gp] : 0;   // unq stays cacheable (k2 re-reads)
    }
    __syncthreads();

    const int qc = t & 7;      // channel quad: channels 4*qc .. 4*qc+3
    const int pr = t >> 3;     // point 0..31 within each iteration group
    const int c0 = qc * 4;
    float w[4][N_IC];
    float b[4];
    #pragma unroll
    for (int j = 0; j < 4; ++j) {
        b[j] = sB[c0 + j];
        #pragma unroll
        for (int k = 0; k < N_IC; ++k) w[j][k] = sW[c0 + j][k];
    }

    // 32 points in flight per iteration, 4 iterations total.
    // sIn reads: 8 distinct rows/wave, 8-lane broadcast each; stride 11 -> conflict-free.
    #pragma unroll
    for (int it = 0; it < PPB; it += (BLK / 8)) {
        const int lp = it + pr;
        const long long gp = base + lp;
        if (gp < (long long)n) {
            f4 v;
            #pragma unroll
            for (int j = 0; j < 4; ++j) {
                float acc = b[j];
                #pragma unroll
                for (int k = 0; k < N_IC; ++k) acc = fmaf(sIn[lp][k], w[j][k], acc);
                v[j] = fmaxf(acc, 0.f);
            }
            // 8 lanes x 16B = 128B per point, full lines, write-once -> NT
            __builtin_nontemporal_store(v, (f4*)&out[gp * 64 + c0]);
            const unsigned pil = (unsigned)sPil[lp];
            // vector filter read: one dwordx4 per thread (128B/point across 8 lanes).
            // Stale-safe: pmax is monotone non-decreasing, stale <= truth.
            // r[j] >= 0 always, so v[j] > r[j] subsumes the old v > 0 check.
            f4 r = *(const f4*)&pmax[pil * N_OC + c0];
            #pragma unroll
            for (int j = 0; j < 4; ++j) {
                if (v[j] > r[j])
                    atomicMax(&pmax[pil * N_OC + c0 + j], __float_as_uint(v[j]));
            }
        }
    }
}

// k2: gather per-pillar max back, write out[:,32:64] as float4 (8 lanes/point),
// persistent grid-stride (cap ~2048 blocks, Guideline 11).
__global__ __launch_bounds__(BLK) void pfn_k2(
    const int* __restrict__ unq, const f4* __restrict__ pmax4,
    f4* __restrict__ out4, int n)
{
    const long long total  = (long long)n * 8;
    const long long stride = (long long)gridDim.x * BLK;
    for (long long tid = (long long)blockIdx.x * BLK + threadIdx.x;
         tid < total; tid += stride) {
        long long p = tid >> 3;          // point index
        int q = (int)(tid & 7);          // which float4 of the 8 in the xmax half-row
        int pil = unq[p];                           // broadcast across 8 lanes
        f4 v = pmax4[(long long)pil * 8 + q];       // 128B row gather, L2/L3-resident
        __builtin_nontemporal_store(v, &out4[p * 16 + 8 + q]);  // full 64B lines
    }
}

extern "C" void kernel_launch(void* const* d_in, const int* in_sizes, int n_in,
                              void* d_out, int out_size, void* d_ws, size_t ws_size,
                              hipStream_t stream) {
    const float* in    = (const float*)d_in[0];
    const int*   unq   = (const int*)d_in[1];
    const float* W     = (const float*)d_in[2];
    const float* gamma = (const float*)d_in[3];
    const float* beta  = (const float*)d_in[4];
    const float* rmean = (const float*)d_in[5];
    const float* rvar  = (const float*)d_in[6];
    const int n = in_sizes[1];                 // 2,000,000 points
    float* out = (float*)d_out;
    unsigned* pmax = (unsigned*)d_ws;

    size_t need = (size_t)NPIL * N_OC * sizeof(unsigned);   // 6.4 MB
    hipMemsetAsync(d_ws, 0, need, stream);

    int g1 = (n + PPB - 1) / PPB;
    pfn_k1<<<g1, BLK, 0, stream>>>(in, unq, W, gamma, beta, rmean, rvar, out, pmax, n);

    pfn_k2<<<2048, BLK, 0, stream>>>(unq, (const f4*)d_ws, (f4*)out, n);
}